// Round 1
// baseline (793.997 us; speedup 1.0000x reference)
//
#include <hip/hip_runtime.h>
#include <math.h>

#define DD   256
#define HHH  96
#define WWW  96
#define NB   8
#define LL   9216            // HHH*WWW
#define NPIX (NB*LL)         // 73728
#define TCH  32              // scan chunk length
#define NCH  (LL/TCH)        // 288

static __device__ __forceinline__ float sigmoidf_(float x) {
    return 1.0f / (1.0f + expf(-x));
}

// spatial index for sequence position t: dir 0 = row-major (t), dir 1 = col-major (w*H+h -> h*W+w)
template<int DIR>
static __device__ __forceinline__ int spidx(int t) {
    if (DIR == 0) return t;
    int w = t / HHH;
    int h = t - w * HHH;
    return h * WWW + w;
}

// ---------------- LayerNorm over channels ----------------
__global__ __launch_bounds__(256) void ln_kernel(const float* __restrict__ x,
                                                 const float* __restrict__ g,
                                                 const float* __restrict__ b,
                                                 float* __restrict__ h) {
    int pix = blockIdx.x;
    int d = threadIdx.x;
    float v = x[(size_t)pix * DD + d];
    float s = v, s2 = v * v;
    #pragma unroll
    for (int o = 32; o > 0; o >>= 1) {
        s  += __shfl_down(s, o, 64);
        s2 += __shfl_down(s2, o, 64);
    }
    __shared__ float ws1[4], ws2[4];
    int wid = d >> 6, lane = d & 63;
    if (lane == 0) { ws1[wid] = s; ws2[wid] = s2; }
    __syncthreads();
    if (d == 0) {
        float a = 0.f, c = 0.f;
        for (int i = 0; i < 4; i++) { a += ws1[i]; c += ws2[i]; }
        ws1[0] = a; ws2[0] = c;
    }
    __syncthreads();
    float mu  = ws1[0] * (1.0f / 256.0f);
    float var = ws2[0] * (1.0f / 256.0f) - mu * mu;
    float r = rsqrtf(var + 1e-5f);
    h[(size_t)pix * DD + d] = (v - mu) * r * g[d] + b[d];
}

// ---------------- fp32 tiled GEMM, 128x128 tile, 8x8/thread ----------------
// MODE 0: xg = A @ Bw + bias ; cols [0,256)->out0 (x_in), cols [256,512)->sigmoid->out1 (gate)
// MODE 1: out0 = x0 + A @ Bw + bias
template<int MODE>
__global__ __launch_bounds__(256) void gemm_kernel(const float* __restrict__ A,
                                                   const float* __restrict__ Bw,
                                                   const float* __restrict__ bias,
                                                   int N,
                                                   float* __restrict__ out0,
                                                   float* __restrict__ out1,
                                                   const float* __restrict__ x0) {
    const int K = 256;
    __shared__ float As[16][132];
    __shared__ float Bs[16][132];
    int tid = threadIdx.x;
    int rowBase = blockIdx.x * 128;
    int colBase = blockIdx.y * 128;
    int a_kq = tid & 3;        // k-quad for A load
    int a_r  = tid >> 2;       // row 0..63
    int b_nq = tid & 31;       // n-quad for B load
    int b_k  = tid >> 5;       // k 0..7
    int tx = tid & 15, ty = tid >> 4;

    float acc[8][8];
    #pragma unroll
    for (int i = 0; i < 8; i++)
        #pragma unroll
        for (int j = 0; j < 8; j++) acc[i][j] = 0.f;

    for (int k0 = 0; k0 < K; k0 += 16) {
        float4 av0 = *(const float4*)&A[(size_t)(rowBase + a_r) * K + k0 + a_kq * 4];
        float4 av1 = *(const float4*)&A[(size_t)(rowBase + a_r + 64) * K + k0 + a_kq * 4];
        float4 bv0 = *(const float4*)&Bw[(size_t)(k0 + b_k) * N + colBase + b_nq * 4];
        float4 bv1 = *(const float4*)&Bw[(size_t)(k0 + b_k + 8) * N + colBase + b_nq * 4];
        __syncthreads();
        As[a_kq * 4 + 0][a_r] = av0.x;
        As[a_kq * 4 + 1][a_r] = av0.y;
        As[a_kq * 4 + 2][a_r] = av0.z;
        As[a_kq * 4 + 3][a_r] = av0.w;
        As[a_kq * 4 + 0][a_r + 64] = av1.x;
        As[a_kq * 4 + 1][a_r + 64] = av1.y;
        As[a_kq * 4 + 2][a_r + 64] = av1.z;
        As[a_kq * 4 + 3][a_r + 64] = av1.w;
        *(float4*)&Bs[b_k][b_nq * 4]     = bv0;
        *(float4*)&Bs[b_k + 8][b_nq * 4] = bv1;
        __syncthreads();
        #pragma unroll
        for (int kk = 0; kk < 16; kk++) {
            float af[8], bf[8];
            float4 t0 = *(const float4*)&As[kk][ty * 4];
            float4 t1 = *(const float4*)&As[kk][64 + ty * 4];
            float4 u0 = *(const float4*)&Bs[kk][tx * 4];
            float4 u1 = *(const float4*)&Bs[kk][64 + tx * 4];
            af[0]=t0.x; af[1]=t0.y; af[2]=t0.z; af[3]=t0.w;
            af[4]=t1.x; af[5]=t1.y; af[6]=t1.z; af[7]=t1.w;
            bf[0]=u0.x; bf[1]=u0.y; bf[2]=u0.z; bf[3]=u0.w;
            bf[4]=u1.x; bf[5]=u1.y; bf[6]=u1.z; bf[7]=u1.w;
            #pragma unroll
            for (int i = 0; i < 8; i++)
                #pragma unroll
                for (int j = 0; j < 8; j++)
                    acc[i][j] += af[i] * bf[j];
        }
    }

    // epilogue: rows = rowBase + ih*64 + ty*4 + ir ; cols = colBase + jh*64 + tx*4 + 0..3
    #pragma unroll
    for (int ih = 0; ih < 2; ih++) {
        #pragma unroll
        for (int ir = 0; ir < 4; ir++) {
            int i = ih * 4 + ir;
            int row = rowBase + ih * 64 + ty * 4 + ir;
            #pragma unroll
            for (int jh = 0; jh < 2; jh++) {
                int n = colBase + jh * 64 + tx * 4;
                float4 bv = *(const float4*)&bias[n];
                float4 v;
                v.x = acc[i][jh * 4 + 0] + bv.x;
                v.y = acc[i][jh * 4 + 1] + bv.y;
                v.z = acc[i][jh * 4 + 2] + bv.z;
                v.w = acc[i][jh * 4 + 3] + bv.w;
                if (MODE == 0) {
                    if (n < 256) {
                        *(float4*)&out0[(size_t)row * 256 + n] = v;
                    } else {
                        v.x = sigmoidf_(v.x); v.y = sigmoidf_(v.y);
                        v.z = sigmoidf_(v.z); v.w = sigmoidf_(v.w);
                        *(float4*)&out1[(size_t)row * 256 + (n - 256)] = v;
                    }
                } else {
                    float4 xv = *(const float4*)&x0[(size_t)row * 256 + n];
                    v.x += xv.x; v.y += xv.y; v.z += xv.z; v.w += xv.w;
                    *(float4*)&out0[(size_t)row * 256 + n] = v;
                }
            }
        }
    }
}

// ---------------- depthwise 3x3 SAME conv + bias + SiLU ----------------
__global__ __launch_bounds__(256) void conv_kernel(const float* __restrict__ xin,
                                                   const float* __restrict__ cw,
                                                   const float* __restrict__ cb,
                                                   float* __restrict__ u) {
    int pix = blockIdx.x;
    int d = threadIdx.x;
    int b = pix / LL;
    int rem = pix - b * LL;
    int h = rem / WWW;
    int w = rem - h * WWW;
    float acc = cb[d];
    #pragma unroll
    for (int kh = 0; kh < 3; kh++) {
        int hh = h + kh - 1;
        if (hh < 0 || hh >= HHH) continue;
        #pragma unroll
        for (int kw = 0; kw < 3; kw++) {
            int ww2 = w + kw - 1;
            if (ww2 < 0 || ww2 >= WWW) continue;
            acc += cw[(kh * 3 + kw) * DD + d] *
                   xin[((size_t)b * LL + hh * WWW + ww2) * DD + d];
        }
    }
    u[(size_t)pix * DD + d] = acc * sigmoidf_(acc);
}

// ---------------- scan pass A: per-chunk fwd/bwd totals ----------------
template<int DIR>
__global__ __launch_bounds__(256) void scan_totals(const float* __restrict__ u,
                                                   const float* __restrict__ a_logit,
                                                   const float* __restrict__ ssm_b,
                                                   float* __restrict__ tot_f,
                                                   float* __restrict__ tot_b) {
    int blk = blockIdx.x;             // b*NCH + c
    int b = blk / NCH, c = blk - b * NCH;
    int d = threadIdx.x;
    float a = sigmoidf_(a_logit[d]);
    a = fminf(fmaxf(a, 1e-4f), 1.0f - 1e-4f);
    float bb = ssm_b[d];
    size_t base = (size_t)b * LL * DD;
    int t0 = c * TCH;
    float v[TCH];
    #pragma unroll
    for (int j = 0; j < TCH; j++)
        v[j] = u[base + (size_t)spidx<DIR>(t0 + j) * DD + d];
    float s = 0.f;
    #pragma unroll
    for (int j = 0; j < TCH; j++) s = a * s + bb * v[j];
    tot_f[(size_t)blk * DD + d] = s;
    s = 0.f;
    #pragma unroll
    for (int j = TCH - 1; j >= 0; j--) s = a * s + bb * v[j];
    tot_b[(size_t)blk * DD + d] = s;
}

// ---------------- scan pass B: cross-chunk carries ----------------
__global__ __launch_bounds__(256) void scan_carries(const float* __restrict__ tot_f,
                                                    const float* __restrict__ tot_b,
                                                    const float* __restrict__ a_logit,
                                                    float* __restrict__ car_f,
                                                    float* __restrict__ car_b) {
    int b = blockIdx.x;     // 0..NB-1
    int d = threadIdx.x;
    float a = sigmoidf_(a_logit[d]);
    a = fminf(fmaxf(a, 1e-4f), 1.0f - 1e-4f);
    float a2 = a * a, a4 = a2 * a2, a8 = a4 * a4, a16 = a8 * a8;
    float q = a16 * a16;    // a^32 == a^TCH
    float P = 0.f;
    for (int c = 0; c < NCH; c++) {
        size_t i = ((size_t)b * NCH + c) * DD + d;
        car_f[i] = P;
        P = q * P + tot_f[i];
    }
    P = 0.f;
    for (int c = NCH - 1; c >= 0; c--) {
        size_t i = ((size_t)b * NCH + c) * DD + d;
        car_b[i] = P;
        P = q * P + tot_b[i];
    }
}

// ---------------- scan pass C: apply carries, emit 0.25*(yf+yb) ----------------
// DIR 0 (row pass): y[idx]  = val
// DIR 1 (col pass): g[idx]  = (y[idx] + val) * gate[idx]
template<int DIR>
__global__ __launch_bounds__(256) void scan_apply(const float* __restrict__ u,
                                                  const float* __restrict__ a_logit,
                                                  const float* __restrict__ ssm_b,
                                                  const float* __restrict__ ssm_c,
                                                  const float* __restrict__ ssm_d,
                                                  const float* __restrict__ car_f,
                                                  const float* __restrict__ car_b,
                                                  float* __restrict__ y,
                                                  const float* __restrict__ gate,
                                                  float* __restrict__ g) {
    int blk = blockIdx.x;
    int b = blk / NCH, c = blk - b * NCH;
    int d = threadIdx.x;
    float a = sigmoidf_(a_logit[d]);
    a = fminf(fmaxf(a, 1e-4f), 1.0f - 1e-4f);
    float bb = ssm_b[d], cc = ssm_c[d], dd = ssm_d[d];
    size_t base = (size_t)b * LL * DD;
    int t0 = c * TCH;
    float v[TCH];
    #pragma unroll
    for (int j = 0; j < TCH; j++)
        v[j] = u[base + (size_t)spidx<DIR>(t0 + j) * DD + d];
    float yf[TCH];
    float s = car_f[(size_t)blk * DD + d];
    #pragma unroll
    for (int j = 0; j < TCH; j++) {
        s = a * s + bb * v[j];
        yf[j] = cc * s + dd * v[j];
    }
    s = car_b[(size_t)blk * DD + d];
    #pragma unroll
    for (int j = TCH - 1; j >= 0; j--) {
        s = a * s + bb * v[j];
        float val = 0.25f * (yf[j] + cc * s + dd * v[j]);
        size_t idx = base + (size_t)spidx<DIR>(t0 + j) * DD + d;
        if (DIR == 0) {
            y[idx] = val;
        } else {
            float t = y[idx] + val;
            g[idx] = t * gate[idx];
        }
    }
}

extern "C" void kernel_launch(void* const* d_in, const int* in_sizes, int n_in,
                              void* d_out, int out_size, void* d_ws, size_t ws_size,
                              hipStream_t stream) {
    const float* x       = (const float*)d_in[0];
    const float* ln_g    = (const float*)d_in[1];
    const float* ln_b    = (const float*)d_in[2];
    const float* w_in    = (const float*)d_in[3];
    const float* b_in    = (const float*)d_in[4];
    const float* conv_w  = (const float*)d_in[5];
    const float* conv_b  = (const float*)d_in[6];
    const float* a_logit = (const float*)d_in[7];
    const float* ssm_b   = (const float*)d_in[8];
    const float* ssm_c   = (const float*)d_in[9];
    const float* ssm_d   = (const float*)d_in[10];
    const float* w_out   = (const float*)d_in[11];
    const float* b_out   = (const float*)d_in[12];
    float* out = (float*)d_out;

    char* ws = (char*)d_ws;
    const size_t SZ = (size_t)NPIX * DD * sizeof(float);          // 75.5 MB
    const size_t TS = (size_t)NB * NCH * DD * sizeof(float);      // 2.36 MB
    float* bufA  = (float*)(ws);                 // h, then u (conv out)
    float* bufB  = (float*)(ws + SZ);            // x_in, then g = y*gate
    float* bufC  = (float*)(ws + 2 * SZ);        // gate
    float* tot_f = (float*)(ws + 3 * SZ);
    float* tot_b = (float*)(ws + 3 * SZ + TS);
    float* car_f = (float*)(ws + 3 * SZ + 2 * TS);
    float* car_b = (float*)(ws + 3 * SZ + 3 * TS);
    float* y = out;                              // d_out doubles as y accumulator

    ln_kernel<<<NPIX, 256, 0, stream>>>(x, ln_g, ln_b, bufA);
    gemm_kernel<0><<<dim3(NPIX / 128, 4), 256, 0, stream>>>(bufA, w_in, b_in, 512,
                                                            bufB, bufC, nullptr);
    conv_kernel<<<NPIX, 256, 0, stream>>>(bufB, conv_w, conv_b, bufA);

    // row-direction bidirectional scan -> y (d_out)
    scan_totals<0><<<NB * NCH, 256, 0, stream>>>(bufA, a_logit, ssm_b, tot_f, tot_b);
    scan_carries<<<NB, 256, 0, stream>>>(tot_f, tot_b, a_logit, car_f, car_b);
    scan_apply<0><<<NB * NCH, 256, 0, stream>>>(bufA, a_logit, ssm_b, ssm_c, ssm_d,
                                                car_f, car_b, y, nullptr, nullptr);
    // col-direction bidirectional scan, accumulate + gate -> g (bufB)
    scan_totals<1><<<NB * NCH, 256, 0, stream>>>(bufA, a_logit, ssm_b, tot_f, tot_b);
    scan_carries<<<NB, 256, 0, stream>>>(tot_f, tot_b, a_logit, car_f, car_b);
    scan_apply<1><<<NB * NCH, 256, 0, stream>>>(bufA, a_logit, ssm_b, ssm_c, ssm_d,
                                                car_f, car_b, y, bufC, bufB);

    // out = x0 + g @ w_out + b_out
    gemm_kernel<1><<<dim3(NPIX / 128, 2), 256, 0, stream>>>(bufB, w_out, b_out, 256,
                                                            out, nullptr, x);
}

// Round 2
// 553.396 us; speedup vs baseline: 1.4348x; 1.4348x over previous
//
#include <hip/hip_runtime.h>
#include <math.h>

#define DD   256
#define HHH  96
#define WWW  96
#define NB   8
#define LL   9216            // HHH*WWW
#define NPIX (NB*LL)         // 73728
#define TCH  32              // scan chunk length
#define NCH  (LL/TCH)        // 288

typedef __bf16 bf16_8 __attribute__((ext_vector_type(8)));
typedef float  f32_4  __attribute__((ext_vector_type(4)));

static __device__ __forceinline__ float sigmoidf_(float x) {
    return 1.0f / (1.0f + expf(-x));
}

template<int DIR>
static __device__ __forceinline__ int spidx(int t) {
    if (DIR == 0) return t;
    int w = t / HHH;
    int h = t - w * HHH;
    return h * WWW + w;
}

// ---------------- weight transpose + bf16 cast ----------------
// w_inT: [512][256] bf16 from w_in [256][512] fp32 ; w_outT: [256][256] from w_out
__global__ __launch_bounds__(256) void wcvt_kernel(const float* __restrict__ w_in,
                                                   const float* __restrict__ w_out,
                                                   __bf16* __restrict__ w_inT,
                                                   __bf16* __restrict__ w_outT) {
    int i = blockIdx.x * 256 + threadIdx.x;   // 0 .. 512*256
    int n = i >> 8, k = i & 255;
    w_inT[i] = (__bf16)w_in[k * 512 + n];
    if (i < 256 * 256) w_outT[i] = (__bf16)w_out[k * 256 + n];
}

// ---------------- LayerNorm over channels -> bf16 ----------------
__global__ __launch_bounds__(256) void ln_kernel(const float* __restrict__ x,
                                                 const float* __restrict__ g,
                                                 const float* __restrict__ b,
                                                 __bf16* __restrict__ h) {
    int pix = blockIdx.x;
    int d = threadIdx.x;
    float v = x[(size_t)pix * DD + d];
    float s = v, s2 = v * v;
    #pragma unroll
    for (int o = 32; o > 0; o >>= 1) {
        s  += __shfl_down(s, o, 64);
        s2 += __shfl_down(s2, o, 64);
    }
    __shared__ float ws1[4], ws2[4];
    int wid = d >> 6, lane = d & 63;
    if (lane == 0) { ws1[wid] = s; ws2[wid] = s2; }
    __syncthreads();
    if (d == 0) {
        float a = 0.f, c = 0.f;
        for (int i = 0; i < 4; i++) { a += ws1[i]; c += ws2[i]; }
        ws1[0] = a; ws2[0] = c;
    }
    __syncthreads();
    float mu  = ws1[0] * (1.0f / 256.0f);
    float var = ws2[0] * (1.0f / 256.0f) - mu * mu;
    float r = rsqrtf(var + 1e-5f);
    h[(size_t)pix * DD + d] = (__bf16)((v - mu) * r * g[d] + b[d]);
}

// ---------------- bf16 MFMA GEMM: C = A @ BT^T (+bias, epilogues) ----------
// A: [M][256] bf16 row-major. BT: [N][256] bf16 (i.e. weights pre-transposed).
// 128x128 block tile, 4 waves, each wave 64x64 (4x4 mfma 16x16x32 tiles).
// MODE 0 (N=512): cols<256 -> out_f (x_in fp32); cols>=256 -> sigmoid -> out_g bf16
// MODE 1 (N=256): out_f = x0 + acc + bias (fp32)
template<int MODE>
__global__ __launch_bounds__(256) void gemm_bf16(const __bf16* __restrict__ A,
                                                 const __bf16* __restrict__ BT,
                                                 const float* __restrict__ bias,
                                                 float* __restrict__ out_f,
                                                 __bf16* __restrict__ out_g,
                                                 const float* __restrict__ x0) {
    const int K = 256;
    __shared__ __bf16 As[128 * 40];   // 128 rows x 32 k, pad to 40
    __shared__ __bf16 Bs[128 * 40];
    int tid = threadIdx.x;
    int lane = tid & 63, wv = tid >> 6;
    int rowBase = blockIdx.x * 128;
    int colBase = blockIdx.y * 128;
    int ldr = tid >> 2;       // 0..63 staging row
    int seg = tid & 3;        // 16B segment within 32-k row

    f32_4 acc[4][4];
    #pragma unroll
    for (int i = 0; i < 4; i++)
        #pragma unroll
        for (int j = 0; j < 4; j++) acc[i][j] = (f32_4){0.f, 0.f, 0.f, 0.f};

    const __bf16* Aip = A + (size_t)(rowBase + ldr) * K + seg * 8;
    const __bf16* Bip = BT + (size_t)(colBase + ldr) * K + seg * 8;
    int m0 = (wv >> 1) * 64, n0 = (wv & 1) * 64;
    int fr = lane & 15, fq = lane >> 4;

    for (int k0 = 0; k0 < K; k0 += 32) {
        uint4 a0 = *(const uint4*)(Aip + k0);
        uint4 a1 = *(const uint4*)(Aip + (size_t)64 * K + k0);
        uint4 b0 = *(const uint4*)(Bip + k0);
        uint4 b1 = *(const uint4*)(Bip + (size_t)64 * K + k0);
        __syncthreads();
        *(uint4*)&As[ldr * 40 + seg * 8]        = a0;
        *(uint4*)&As[(ldr + 64) * 40 + seg * 8] = a1;
        *(uint4*)&Bs[ldr * 40 + seg * 8]        = b0;
        *(uint4*)&Bs[(ldr + 64) * 40 + seg * 8] = b1;
        __syncthreads();
        bf16_8 af[4], bb[4];
        #pragma unroll
        for (int mi = 0; mi < 4; mi++)
            af[mi] = *(const bf16_8*)&As[(m0 + mi * 16 + fr) * 40 + fq * 8];
        #pragma unroll
        for (int ni = 0; ni < 4; ni++)
            bb[ni] = *(const bf16_8*)&Bs[(n0 + ni * 16 + fr) * 40 + fq * 8];
        #pragma unroll
        for (int mi = 0; mi < 4; mi++)
            #pragma unroll
            for (int ni = 0; ni < 4; ni++)
                acc[mi][ni] = __builtin_amdgcn_mfma_f32_16x16x32_bf16(
                    af[mi], bb[ni], acc[mi][ni], 0, 0, 0);
    }

    // epilogue: C/D layout col=lane&15, row=(lane>>4)*4+reg
    int rowW = rowBase + m0 + fq * 4;
    int colW = colBase + n0 + fr;
    #pragma unroll
    for (int mi = 0; mi < 4; mi++) {
        #pragma unroll
        for (int ni = 0; ni < 4; ni++) {
            int col = colW + ni * 16;
            float bv = bias[col];
            #pragma unroll
            for (int r = 0; r < 4; r++) {
                int row = rowW + mi * 16 + r;
                float v = acc[mi][ni][r] + bv;
                if (MODE == 0) {
                    if (col < 256) {
                        out_f[(size_t)row * 256 + col] = v;
                    } else {
                        out_g[(size_t)row * 256 + (col - 256)] = (__bf16)sigmoidf_(v);
                    }
                } else {
                    out_f[(size_t)row * 256 + col] =
                        v + x0[(size_t)row * 256 + col];
                }
            }
        }
    }
}

// ---------------- depthwise 3x3 SAME conv + bias + SiLU ----------------
__global__ __launch_bounds__(256) void conv_kernel(const float* __restrict__ xin,
                                                   const float* __restrict__ cw,
                                                   const float* __restrict__ cb,
                                                   float* __restrict__ u) {
    int pix = blockIdx.x;
    int d = threadIdx.x;
    int b = pix / LL;
    int rem = pix - b * LL;
    int h = rem / WWW;
    int w = rem - h * WWW;
    float acc = cb[d];
    #pragma unroll
    for (int kh = 0; kh < 3; kh++) {
        int hh = h + kh - 1;
        if (hh < 0 || hh >= HHH) continue;
        #pragma unroll
        for (int kw = 0; kw < 3; kw++) {
            int ww2 = w + kw - 1;
            if (ww2 < 0 || ww2 >= WWW) continue;
            acc += cw[(kh * 3 + kw) * DD + d] *
                   xin[((size_t)b * LL + hh * WWW + ww2) * DD + d];
        }
    }
    u[(size_t)pix * DD + d] = acc * sigmoidf_(acc);
}

// ---------------- scan pass A: per-chunk fwd/bwd totals ----------------
template<int DIR>
__global__ __launch_bounds__(256) void scan_totals(const float* __restrict__ u,
                                                   const float* __restrict__ a_logit,
                                                   const float* __restrict__ ssm_b,
                                                   float* __restrict__ tot_f,
                                                   float* __restrict__ tot_b) {
    int blk = blockIdx.x;
    int b = blk / NCH, c = blk - b * NCH;
    int d = threadIdx.x;
    float a = sigmoidf_(a_logit[d]);
    a = fminf(fmaxf(a, 1e-4f), 1.0f - 1e-4f);
    float bb = ssm_b[d];
    size_t base = (size_t)b * LL * DD;
    int t0 = c * TCH;
    float v[TCH];
    #pragma unroll
    for (int j = 0; j < TCH; j++)
        v[j] = u[base + (size_t)spidx<DIR>(t0 + j) * DD + d];
    float s = 0.f;
    #pragma unroll
    for (int j = 0; j < TCH; j++) s = a * s + bb * v[j];
    tot_f[(size_t)blk * DD + d] = s;
    s = 0.f;
    #pragma unroll
    for (int j = TCH - 1; j >= 0; j--) s = a * s + bb * v[j];
    tot_b[(size_t)blk * DD + d] = s;
}

// ---------------- scan pass B: cross-chunk carries (fwd/bwd split by blockIdx.y) ----
__global__ __launch_bounds__(256) void scan_carries(const float* __restrict__ tot_f,
                                                    const float* __restrict__ tot_b,
                                                    const float* __restrict__ a_logit,
                                                    float* __restrict__ car_f,
                                                    float* __restrict__ car_b) {
    int b = blockIdx.x;
    int d = threadIdx.x;
    float a = sigmoidf_(a_logit[d]);
    a = fminf(fmaxf(a, 1e-4f), 1.0f - 1e-4f);
    float a2 = a * a, a4 = a2 * a2, a8 = a4 * a4, a16 = a8 * a8;
    float q = a16 * a16;    // a^TCH
    if (blockIdx.y == 0) {
        float P = 0.f;
        for (int c = 0; c < NCH; c++) {
            size_t i = ((size_t)b * NCH + c) * DD + d;
            car_f[i] = P;
            P = q * P + tot_f[i];
        }
    } else {
        float P = 0.f;
        for (int c = NCH - 1; c >= 0; c--) {
            size_t i = ((size_t)b * NCH + c) * DD + d;
            car_b[i] = P;
            P = q * P + tot_b[i];
        }
    }
}

// ---------------- scan pass C: apply carries, emit 0.25*(yf+yb) ----------------
// DIR 0: y[idx] = val (fp32)
// DIR 1: g[idx] = bf16((y[idx] + val) * gate[idx])
template<int DIR>
__global__ __launch_bounds__(256) void scan_apply(const float* __restrict__ u,
                                                  const float* __restrict__ a_logit,
                                                  const float* __restrict__ ssm_b,
                                                  const float* __restrict__ ssm_c,
                                                  const float* __restrict__ ssm_d,
                                                  const float* __restrict__ car_f,
                                                  const float* __restrict__ car_b,
                                                  float* __restrict__ y,
                                                  const __bf16* __restrict__ gate,
                                                  __bf16* __restrict__ g) {
    int blk = blockIdx.x;
    int b = blk / NCH, c = blk - b * NCH;
    int d = threadIdx.x;
    float a = sigmoidf_(a_logit[d]);
    a = fminf(fmaxf(a, 1e-4f), 1.0f - 1e-4f);
    float bb = ssm_b[d], cc = ssm_c[d], dd = ssm_d[d];
    size_t base = (size_t)b * LL * DD;
    int t0 = c * TCH;
    float v[TCH];
    #pragma unroll
    for (int j = 0; j < TCH; j++)
        v[j] = u[base + (size_t)spidx<DIR>(t0 + j) * DD + d];
    float yf[TCH];
    float s = car_f[(size_t)blk * DD + d];
    #pragma unroll
    for (int j = 0; j < TCH; j++) {
        s = a * s + bb * v[j];
        yf[j] = cc * s + dd * v[j];
    }
    s = car_b[(size_t)blk * DD + d];
    #pragma unroll
    for (int j = TCH - 1; j >= 0; j--) {
        s = a * s + bb * v[j];
        float val = 0.25f * (yf[j] + cc * s + dd * v[j]);
        size_t idx = base + (size_t)spidx<DIR>(t0 + j) * DD + d;
        if (DIR == 0) {
            y[idx] = val;
        } else {
            float t = y[idx] + val;
            g[idx] = (__bf16)(t * (float)gate[idx]);
        }
    }
}

extern "C" void kernel_launch(void* const* d_in, const int* in_sizes, int n_in,
                              void* d_out, int out_size, void* d_ws, size_t ws_size,
                              hipStream_t stream) {
    const float* x       = (const float*)d_in[0];
    const float* ln_g    = (const float*)d_in[1];
    const float* ln_b    = (const float*)d_in[2];
    const float* w_in    = (const float*)d_in[3];
    const float* b_in    = (const float*)d_in[4];
    const float* conv_w  = (const float*)d_in[5];
    const float* conv_b  = (const float*)d_in[6];
    const float* a_logit = (const float*)d_in[7];
    const float* ssm_b   = (const float*)d_in[8];
    const float* ssm_c   = (const float*)d_in[9];
    const float* ssm_d   = (const float*)d_in[10];
    const float* w_out   = (const float*)d_in[11];
    const float* b_out   = (const float*)d_in[12];
    float* out = (float*)d_out;

    char* ws = (char*)d_ws;
    const size_t SZF = (size_t)NPIX * DD * sizeof(float);     // 75.5 MB
    const size_t SZH = (size_t)NPIX * DD * sizeof(__bf16);    // 37.7 MB
    const size_t TS  = (size_t)NB * NCH * DD * sizeof(float); // 2.36 MB

    float*  uBuf   = (float*)(ws);                    // conv output (fp32)
    float*  xinBuf = (float*)(ws + SZF);              // x_in (fp32); dead after conv
    // scan scratch overlaps xinBuf (only used after conv completes)
    float*  tot_f  = xinBuf;
    float*  tot_b  = (float*)((char*)xinBuf + TS);
    float*  car_f  = (float*)((char*)xinBuf + 2 * TS);
    float*  car_b  = (float*)((char*)xinBuf + 3 * TS);
    __bf16* gateB  = (__bf16*)(ws + 2 * SZF);         // gate (bf16)
    __bf16* hB     = (__bf16*)(ws + 2 * SZF + SZH);   // h (bf16), reused as g (bf16)
    __bf16* w_inT  = (__bf16*)(ws + 2 * SZF + 2 * SZH);
    __bf16* w_outT = w_inT + 512 * 256;
    float* y = out;

    wcvt_kernel<<<512, 256, 0, stream>>>(w_in, w_out, w_inT, w_outT);
    ln_kernel<<<NPIX, 256, 0, stream>>>(x, ln_g, ln_b, hB);
    gemm_bf16<0><<<dim3(NPIX / 128, 4), 256, 0, stream>>>(hB, w_inT, b_in,
                                                          xinBuf, gateB, nullptr);
    conv_kernel<<<NPIX, 256, 0, stream>>>(xinBuf, conv_w, conv_b, uBuf);

    // row-direction bidirectional scan -> y (d_out)
    scan_totals<0><<<NB * NCH, 256, 0, stream>>>(uBuf, a_logit, ssm_b, tot_f, tot_b);
    scan_carries<<<dim3(NB, 2), 256, 0, stream>>>(tot_f, tot_b, a_logit, car_f, car_b);
    scan_apply<0><<<NB * NCH, 256, 0, stream>>>(uBuf, a_logit, ssm_b, ssm_c, ssm_d,
                                                car_f, car_b, y, nullptr, nullptr);
    // col-direction bidirectional scan, accumulate + gate -> g (bf16, reuses h slot)
    scan_totals<1><<<NB * NCH, 256, 0, stream>>>(uBuf, a_logit, ssm_b, tot_f, tot_b);
    scan_carries<<<dim3(NB, 2), 256, 0, stream>>>(tot_f, tot_b, a_logit, car_f, car_b);
    scan_apply<1><<<NB * NCH, 256, 0, stream>>>(uBuf, a_logit, ssm_b, ssm_c, ssm_d,
                                                car_f, car_b, y, gateB, hB);

    // out = x0 + g @ w_out + b_out
    gemm_bf16<1><<<dim3(NPIX / 128, 2), 256, 0, stream>>>(hB, w_outT, b_out,
                                                          out, nullptr, x);
}

// Round 3
// 449.154 us; speedup vs baseline: 1.7678x; 1.2321x over previous
//
#include <hip/hip_runtime.h>
#include <math.h>

#define DD   256
#define HHH  96
#define WWW  96
#define NB   8
#define LL   9216            // HHH*WWW
#define NPIX (NB*LL)         // 73728
#define TCH  32              // scan chunk length
#define NCH  (LL/TCH)        // 288

typedef __bf16 bf16_8 __attribute__((ext_vector_type(8)));
typedef float  f32_4  __attribute__((ext_vector_type(4)));

static __device__ __forceinline__ float sigmoidf_(float x) {
    return 1.0f / (1.0f + expf(-x));
}

template<int DIR>
static __device__ __forceinline__ int spidx(int t) {
    if (DIR == 0) return t;
    int w = t / HHH;
    int h = t - w * HHH;
    return h * WWW + w;
}

// ---------------- weight transpose + bf16 cast ----------------
__global__ __launch_bounds__(256) void wcvt_kernel(const float* __restrict__ w_in,
                                                   const float* __restrict__ w_out,
                                                   __bf16* __restrict__ w_inT,
                                                   __bf16* __restrict__ w_outT) {
    int i = blockIdx.x * 256 + threadIdx.x;
    int n = i >> 8, k = i & 255;
    w_inT[i] = (__bf16)w_in[k * 512 + n];
    if (i < 256 * 256) w_outT[i] = (__bf16)w_out[k * 256 + n];
}

// ---------------- LayerNorm over channels -> bf16 ----------------
__global__ __launch_bounds__(256) void ln_kernel(const float* __restrict__ x,
                                                 const float* __restrict__ g,
                                                 const float* __restrict__ b,
                                                 __bf16* __restrict__ h) {
    int pix = blockIdx.x;
    int d = threadIdx.x;
    float v = x[(size_t)pix * DD + d];
    float s = v, s2 = v * v;
    #pragma unroll
    for (int o = 32; o > 0; o >>= 1) {
        s  += __shfl_down(s, o, 64);
        s2 += __shfl_down(s2, o, 64);
    }
    __shared__ float ws1[4], ws2[4];
    int wid = d >> 6, lane = d & 63;
    if (lane == 0) { ws1[wid] = s; ws2[wid] = s2; }
    __syncthreads();
    if (d == 0) {
        float a = 0.f, c = 0.f;
        for (int i = 0; i < 4; i++) { a += ws1[i]; c += ws2[i]; }
        ws1[0] = a; ws2[0] = c;
    }
    __syncthreads();
    float mu  = ws1[0] * (1.0f / 256.0f);
    float var = ws2[0] * (1.0f / 256.0f) - mu * mu;
    float r = rsqrtf(var + 1e-5f);
    h[(size_t)pix * DD + d] = (__bf16)((v - mu) * r * g[d] + b[d]);
}

// ---------------- bf16 MFMA GEMM ----------
// MODE 0 (N=512): cols<256 -> x_in (bf16); cols>=256 -> sigmoid -> gate (bf16)
// MODE 1 (N=256): out_f32 = x0 + acc + bias
template<int MODE>
__global__ __launch_bounds__(256) void gemm_bf16(const __bf16* __restrict__ A,
                                                 const __bf16* __restrict__ BT,
                                                 const float* __restrict__ bias,
                                                 __bf16* __restrict__ out_xin,
                                                 __bf16* __restrict__ out_gate,
                                                 float* __restrict__ out_f32,
                                                 const float* __restrict__ x0) {
    const int K = 256;
    __shared__ __bf16 As[128 * 40];
    __shared__ __bf16 Bs[128 * 40];
    int tid = threadIdx.x;
    int lane = tid & 63, wv = tid >> 6;
    int rowBase = blockIdx.x * 128;
    int colBase = blockIdx.y * 128;
    int ldr = tid >> 2;
    int seg = tid & 3;

    f32_4 acc[4][4];
    #pragma unroll
    for (int i = 0; i < 4; i++)
        #pragma unroll
        for (int j = 0; j < 4; j++) acc[i][j] = (f32_4){0.f, 0.f, 0.f, 0.f};

    const __bf16* Aip = A + (size_t)(rowBase + ldr) * K + seg * 8;
    const __bf16* Bip = BT + (size_t)(colBase + ldr) * K + seg * 8;
    int m0 = (wv >> 1) * 64, n0 = (wv & 1) * 64;
    int fr = lane & 15, fq = lane >> 4;

    for (int k0 = 0; k0 < K; k0 += 32) {
        uint4 a0 = *(const uint4*)(Aip + k0);
        uint4 a1 = *(const uint4*)(Aip + (size_t)64 * K + k0);
        uint4 b0 = *(const uint4*)(Bip + k0);
        uint4 b1 = *(const uint4*)(Bip + (size_t)64 * K + k0);
        __syncthreads();
        *(uint4*)&As[ldr * 40 + seg * 8]        = a0;
        *(uint4*)&As[(ldr + 64) * 40 + seg * 8] = a1;
        *(uint4*)&Bs[ldr * 40 + seg * 8]        = b0;
        *(uint4*)&Bs[(ldr + 64) * 40 + seg * 8] = b1;
        __syncthreads();
        bf16_8 af[4], bb[4];
        #pragma unroll
        for (int mi = 0; mi < 4; mi++)
            af[mi] = *(const bf16_8*)&As[(m0 + mi * 16 + fr) * 40 + fq * 8];
        #pragma unroll
        for (int ni = 0; ni < 4; ni++)
            bb[ni] = *(const bf16_8*)&Bs[(n0 + ni * 16 + fr) * 40 + fq * 8];
        #pragma unroll
        for (int mi = 0; mi < 4; mi++)
            #pragma unroll
            for (int ni = 0; ni < 4; ni++)
                acc[mi][ni] = __builtin_amdgcn_mfma_f32_16x16x32_bf16(
                    af[mi], bb[ni], acc[mi][ni], 0, 0, 0);
    }

    int rowW = rowBase + m0 + fq * 4;
    int colW = colBase + n0 + fr;
    #pragma unroll
    for (int mi = 0; mi < 4; mi++) {
        #pragma unroll
        for (int ni = 0; ni < 4; ni++) {
            int col = colW + ni * 16;
            float bv = bias[col];
            #pragma unroll
            for (int r = 0; r < 4; r++) {
                int row = rowW + mi * 16 + r;
                float v = acc[mi][ni][r] + bv;
                if (MODE == 0) {
                    if (col < 256) {
                        out_xin[(size_t)row * 256 + col] = (__bf16)v;
                    } else {
                        out_gate[(size_t)row * 256 + (col - 256)] = (__bf16)sigmoidf_(v);
                    }
                } else {
                    out_f32[(size_t)row * 256 + col] = v + x0[(size_t)row * 256 + col];
                }
            }
        }
    }
}

// ---------------- fused depthwise 3x3 conv + SiLU + row-scan chunk totals ----
// grid: (WWW/TCH=3, HHH, NB), block 256 (=d). Sliding 3-row column window:
// 3 loads per output instead of 9.
static __device__ __forceinline__ void loadcol(const __bf16* __restrict__ xin,
                                               int b, int h, int w, int d,
                                               float c[3]) {
    if (w < 0 || w >= WWW) { c[0] = c[1] = c[2] = 0.f; return; }
    size_t base = ((size_t)b * LL + (size_t)h * WWW + w) * DD + d;
    c[0] = (h > 0)       ? (float)xin[base - (size_t)WWW * DD] : 0.f;
    c[1] = (float)xin[base];
    c[2] = (h + 1 < HHH) ? (float)xin[base + (size_t)WWW * DD] : 0.f;
}

__global__ __launch_bounds__(256) void conv_tot_kernel(const __bf16* __restrict__ xin,
                                                       const float* __restrict__ cw,
                                                       const float* __restrict__ cb,
                                                       const float* __restrict__ a_logit,
                                                       const float* __restrict__ ssm_b,
                                                       __bf16* __restrict__ u,
                                                       float* __restrict__ tot_f,
                                                       float* __restrict__ tot_b) {
    int cx = blockIdx.x, h = blockIdx.y, b = blockIdx.z;
    int d = threadIdx.x;
    int w0 = cx * TCH;
    float k[9];
    #pragma unroll
    for (int i = 0; i < 9; i++) k[i] = cw[i * DD + d];
    float bias = cb[d];
    float a = sigmoidf_(a_logit[d]);
    a = fminf(fmaxf(a, 1e-4f), 1.0f - 1e-4f);
    float bb = ssm_b[d];

    float cl[3], cc[3], cr[3];
    loadcol(xin, b, h, w0 - 1, d, cl);
    loadcol(xin, b, h, w0,     d, cc);
    loadcol(xin, b, h, w0 + 1, d, cr);

    float v[TCH];
    float sf = 0.f;
    size_t outBase = ((size_t)b * LL + (size_t)h * WWW + w0) * DD + d;
    #pragma unroll
    for (int j = 0; j < TCH; j++) {
        float nx[3];
        loadcol(xin, b, h, w0 + j + 2, d, nx);   // prefetch next column
        float acc = bias;
        acc += k[0] * cl[0] + k[1] * cc[0] + k[2] * cr[0];
        acc += k[3] * cl[1] + k[4] * cc[1] + k[5] * cr[1];
        acc += k[6] * cl[2] + k[7] * cc[2] + k[8] * cr[2];
        float uv = acc * sigmoidf_(acc);
        v[j] = uv;
        u[outBase + (size_t)j * DD] = (__bf16)uv;
        sf = a * sf + bb * uv;
        cl[0] = cc[0]; cl[1] = cc[1]; cl[2] = cc[2];
        cc[0] = cr[0]; cc[1] = cr[1]; cc[2] = cr[2];
        cr[0] = nx[0]; cr[1] = nx[1]; cr[2] = nx[2];
    }
    int chunk = h * 3 + cx;                       // row-major chunk id
    tot_f[((size_t)b * NCH + chunk) * DD + d] = sf;
    float sb = 0.f;
    #pragma unroll
    for (int j = TCH - 1; j >= 0; j--) sb = a * sb + bb * v[j];
    tot_b[((size_t)b * NCH + chunk) * DD + d] = sb;
}

// ---------------- scan pass A (col direction only now) ----------------
__global__ __launch_bounds__(256) void scan_totals_col(const __bf16* __restrict__ u,
                                                       const float* __restrict__ a_logit,
                                                       const float* __restrict__ ssm_b,
                                                       float* __restrict__ tot_f,
                                                       float* __restrict__ tot_b) {
    int blk = blockIdx.x;
    int b = blk / NCH, c = blk - b * NCH;
    int d = threadIdx.x;
    float a = sigmoidf_(a_logit[d]);
    a = fminf(fmaxf(a, 1e-4f), 1.0f - 1e-4f);
    float bb = ssm_b[d];
    size_t base = (size_t)b * LL * DD;
    int t0 = c * TCH;
    float v[TCH];
    #pragma unroll
    for (int j = 0; j < TCH; j++)
        v[j] = (float)u[base + (size_t)spidx<1>(t0 + j) * DD + d];
    float s = 0.f;
    #pragma unroll
    for (int j = 0; j < TCH; j++) s = a * s + bb * v[j];
    tot_f[(size_t)blk * DD + d] = s;
    s = 0.f;
    #pragma unroll
    for (int j = TCH - 1; j >= 0; j--) s = a * s + bb * v[j];
    tot_b[(size_t)blk * DD + d] = s;
}

// ---------------- scan pass B: all 4 carry scans in one dispatch -----------
// variant = blockIdx.y: 0=row-fwd 1=row-bwd 2=col-fwd 3=col-bwd.
// tot_all/car_all: [variant][NB][NCH][DD]. Batch-8 loads to hide latency.
__global__ __launch_bounds__(256) void scan_carries(const float* __restrict__ tot_all,
                                                    const float* __restrict__ a_logit,
                                                    float* __restrict__ car_all) {
    int b = blockIdx.x;
    int var = blockIdx.y;
    int d = threadIdx.x;
    float a = sigmoidf_(a_logit[d]);
    a = fminf(fmaxf(a, 1e-4f), 1.0f - 1e-4f);
    float a2 = a * a, a4 = a2 * a2, a8 = a4 * a4, a16 = a8 * a8;
    float q = a16 * a16;    // a^TCH
    const float* tot = tot_all + (size_t)var * NB * NCH * DD + (size_t)b * NCH * DD + d;
    float* car = car_all + (size_t)var * NB * NCH * DD + (size_t)b * NCH * DD + d;
    float P = 0.f;
    if ((var & 1) == 0) {
        for (int c0 = 0; c0 < NCH; c0 += 8) {
            float t[8];
            #pragma unroll
            for (int j = 0; j < 8; j++) t[j] = tot[(size_t)(c0 + j) * DD];
            #pragma unroll
            for (int j = 0; j < 8; j++) {
                car[(size_t)(c0 + j) * DD] = P;
                P = q * P + t[j];
            }
        }
    } else {
        for (int c0 = NCH - 8; c0 >= 0; c0 -= 8) {
            float t[8];
            #pragma unroll
            for (int j = 0; j < 8; j++) t[j] = tot[(size_t)(c0 + j) * DD];
            #pragma unroll
            for (int j = 7; j >= 0; j--) {
                car[(size_t)(c0 + j) * DD] = P;
                P = q * P + t[j];
            }
        }
    }
}

// ---------------- scan pass C: apply carries, emit 0.25*(yf+yb) ----------------
// DIR 0: y[idx] = val (fp32, d_out buffer)
// DIR 1: g[idx] = bf16((y[idx] + val) * gate[idx])
template<int DIR>
__global__ __launch_bounds__(256) void scan_apply(const __bf16* __restrict__ u,
                                                  const float* __restrict__ a_logit,
                                                  const float* __restrict__ ssm_b,
                                                  const float* __restrict__ ssm_c,
                                                  const float* __restrict__ ssm_d,
                                                  const float* __restrict__ car_f,
                                                  const float* __restrict__ car_b,
                                                  float* __restrict__ y,
                                                  const __bf16* __restrict__ gate,
                                                  __bf16* __restrict__ g) {
    int blk = blockIdx.x;
    int b = blk / NCH, c = blk - b * NCH;
    int d = threadIdx.x;
    float a = sigmoidf_(a_logit[d]);
    a = fminf(fmaxf(a, 1e-4f), 1.0f - 1e-4f);
    float bb = ssm_b[d], cc = ssm_c[d], dd = ssm_d[d];
    size_t base = (size_t)b * LL * DD;
    int t0 = c * TCH;
    float v[TCH];
    #pragma unroll
    for (int j = 0; j < TCH; j++)
        v[j] = (float)u[base + (size_t)spidx<DIR>(t0 + j) * DD + d];
    float yf[TCH];
    float s = car_f[(size_t)blk * DD + d];
    #pragma unroll
    for (int j = 0; j < TCH; j++) {
        s = a * s + bb * v[j];
        yf[j] = cc * s + dd * v[j];
    }
    s = car_b[(size_t)blk * DD + d];
    #pragma unroll
    for (int j = TCH - 1; j >= 0; j--) {
        s = a * s + bb * v[j];
        float val = 0.25f * (yf[j] + cc * s + dd * v[j]);
        size_t idx = base + (size_t)spidx<DIR>(t0 + j) * DD + d;
        if (DIR == 0) {
            y[idx] = val;
        } else {
            float t = y[idx] + val;
            g[idx] = (__bf16)(t * (float)gate[idx]);
        }
    }
}

extern "C" void kernel_launch(void* const* d_in, const int* in_sizes, int n_in,
                              void* d_out, int out_size, void* d_ws, size_t ws_size,
                              hipStream_t stream) {
    const float* x       = (const float*)d_in[0];
    const float* ln_g    = (const float*)d_in[1];
    const float* ln_b    = (const float*)d_in[2];
    const float* w_in    = (const float*)d_in[3];
    const float* b_in    = (const float*)d_in[4];
    const float* conv_w  = (const float*)d_in[5];
    const float* conv_b  = (const float*)d_in[6];
    const float* a_logit = (const float*)d_in[7];
    const float* ssm_b   = (const float*)d_in[8];
    const float* ssm_c   = (const float*)d_in[9];
    const float* ssm_d   = (const float*)d_in[10];
    const float* w_out   = (const float*)d_in[11];
    const float* b_out   = (const float*)d_in[12];
    float* out = (float*)d_out;

    char* ws = (char*)d_ws;
    const size_t SZH = (size_t)NPIX * DD * sizeof(__bf16);    // 37.7 MB
    const size_t TS  = (size_t)NB * NCH * DD * sizeof(float); // 2.36 MB

    __bf16* hB     = (__bf16*)(ws);                  // h, later reused as g
    __bf16* xinB   = (__bf16*)(ws + SZH);            // x_in bf16
    __bf16* uB     = (__bf16*)(ws + 2 * SZH);        // conv output bf16
    __bf16* gateB  = (__bf16*)(ws + 3 * SZH);        // gate bf16
    float*  tot    = (float*)(ws + 4 * SZH);         // [4][NB][NCH][DD]
    float*  car    = (float*)(ws + 4 * SZH + 4 * TS);
    __bf16* w_inT  = (__bf16*)(ws + 4 * SZH + 8 * TS);
    __bf16* w_outT = w_inT + 512 * 256;
    float* y = out;

    wcvt_kernel<<<512, 256, 0, stream>>>(w_in, w_out, w_inT, w_outT);
    ln_kernel<<<NPIX, 256, 0, stream>>>(x, ln_g, ln_b, hB);
    gemm_bf16<0><<<dim3(NPIX / 128, 4), 256, 0, stream>>>(hB, w_inT, b_in,
                                                          xinB, gateB, nullptr, nullptr);
    // fused conv + row totals
    conv_tot_kernel<<<dim3(WWW / TCH, HHH, NB), 256, 0, stream>>>(
        xinB, conv_w, conv_b, a_logit, ssm_b, uB,
        tot + 0 * (size_t)NB * NCH * DD, tot + 1 * (size_t)NB * NCH * DD);
    // col totals
    scan_totals_col<<<NB * NCH, 256, 0, stream>>>(
        uB, a_logit, ssm_b,
        tot + 2 * (size_t)NB * NCH * DD, tot + 3 * (size_t)NB * NCH * DD);
    // all 4 carry scans
    scan_carries<<<dim3(NB, 4), 256, 0, stream>>>(tot, a_logit, car);
    // row apply -> y (fp32, d_out)
    scan_apply<0><<<NB * NCH, 256, 0, stream>>>(
        uB, a_logit, ssm_b, ssm_c, ssm_d,
        car + 0 * (size_t)NB * NCH * DD, car + 1 * (size_t)NB * NCH * DD,
        y, nullptr, nullptr);
    // col apply + gate -> g (bf16, reuses h slot)
    scan_apply<1><<<NB * NCH, 256, 0, stream>>>(
        uB, a_logit, ssm_b, ssm_c, ssm_d,
        car + 2 * (size_t)NB * NCH * DD, car + 3 * (size_t)NB * NCH * DD,
        y, gateB, hB);
    // out = x0 + g @ w_out + b_out
    gemm_bf16<1><<<dim3(NPIX / 128, 2), 256, 0, stream>>>(hB, w_outT, b_out,
                                                          nullptr, nullptr, out, x);
}